// Round 1
// baseline (692.785 us; speedup 1.0000x reference)
//
#include <hip/hip_runtime.h>
#include <hip/hip_bf16.h>

#define HOPS 3
#define NA 50000
#define NP 100000
#define NIN 256
#define NHID 128
#define NOUT 64
#define NEDGE 500000
#define CAP_A 64
#define CAP_P 40

// ---------- projection: C[M,128] = relu(A[M,256] @ W[256,128] + b) ----------
// BM=64, BN=128, BK=32, 256 threads, each thread 8 rows x 4 cols
__global__ __launch_bounds__(256) void proj_kernel(const float* __restrict__ A,
                                                   const float* __restrict__ W,
                                                   const float* __restrict__ b,
                                                   float* __restrict__ C, int M)
{
    __shared__ float As[32][68];   // [k][m] transposed, padded (stride 68 keeps float4 align)
    __shared__ float Bs[32][132];  // [k][n] padded
    int tid = threadIdx.x;
    int br = blockIdx.x * 64;
    int tx = tid & 31;             // col group
    int ty = tid >> 5;             // row group 0..7
    int col = tx * 4;
    int row0 = ty * 8;
    float acc[8][4] = {};
    for (int k0 = 0; k0 < NIN; k0 += 32) {
        #pragma unroll
        for (int i = 0; i < 2; ++i) {          // A tile 64x32 = 512 float4
            int f = tid + i * 256;
            int r = f >> 3;
            int k4 = (f & 7) * 4;
            int gr = br + r; if (gr >= M) gr = M - 1;
            const float4 v = *(const float4*)(A + (size_t)gr * NIN + k0 + k4);
            As[k4 + 0][r] = v.x; As[k4 + 1][r] = v.y;
            As[k4 + 2][r] = v.z; As[k4 + 3][r] = v.w;
        }
        #pragma unroll
        for (int i = 0; i < 4; ++i) {          // B tile 32x128 = 1024 float4
            int f = tid + i * 256;
            int k = f >> 5;
            int n4 = (f & 31) * 4;
            const float4 v = *(const float4*)(W + (size_t)(k0 + k) * NHID + n4);
            *(float4*)&Bs[k][n4] = v;
        }
        __syncthreads();
        #pragma unroll
        for (int kk = 0; kk < 32; ++kk) {
            float4 a0 = *(const float4*)&As[kk][row0];
            float4 a1 = *(const float4*)&As[kk][row0 + 4];
            float4 bv = *(const float4*)&Bs[kk][col];
            float ar[8] = {a0.x, a0.y, a0.z, a0.w, a1.x, a1.y, a1.z, a1.w};
            float bc[4] = {bv.x, bv.y, bv.z, bv.w};
            #pragma unroll
            for (int r = 0; r < 8; ++r)
                #pragma unroll
                for (int c = 0; c < 4; ++c)
                    acc[r][c] += ar[r] * bc[c];
        }
        __syncthreads();
    }
    float4 bias = *(const float4*)(b + col);
    float bb[4] = {bias.x, bias.y, bias.z, bias.w};
    #pragma unroll
    for (int r = 0; r < 8; ++r) {
        int gr = br + row0 + r;
        if (gr < M) {
            float4 o;
            o.x = fmaxf(acc[r][0] + bb[0], 0.f);
            o.y = fmaxf(acc[r][1] + bb[1], 0.f);
            o.z = fmaxf(acc[r][2] + bb[2], 0.f);
            o.w = fmaxf(acc[r][3] + bb[3], 0.f);
            *(float4*)(C + (size_t)gr * NHID + col) = o;
        }
    }
}

// ---------- output: C[M,64] = A[M,128] @ W[128,64] + b ----------
__global__ __launch_bounds__(256) void out_kernel(const float* __restrict__ A,
                                                  const float* __restrict__ W,
                                                  const float* __restrict__ b,
                                                  float* __restrict__ C, int M)
{
    __shared__ float As[32][68];
    __shared__ float Bs[32][68];
    int tid = threadIdx.x;
    int br = blockIdx.x * 64;
    int tx = tid & 15, ty = tid >> 4;
    int col = tx * 4, row0 = ty * 4;
    float acc[4][4] = {};
    for (int k0 = 0; k0 < NHID; k0 += 32) {
        #pragma unroll
        for (int i = 0; i < 2; ++i) {          // A tile 64x32
            int f = tid + i * 256;
            int r = f >> 3;
            int k4 = (f & 7) * 4;
            int gr = br + r; if (gr >= M) gr = M - 1;
            const float4 v = *(const float4*)(A + (size_t)gr * NHID + k0 + k4);
            As[k4 + 0][r] = v.x; As[k4 + 1][r] = v.y;
            As[k4 + 2][r] = v.z; As[k4 + 3][r] = v.w;
        }
        #pragma unroll
        for (int i = 0; i < 2; ++i) {          // B tile 32x64
            int f = tid + i * 256;
            int k = f >> 4;
            int n4 = (f & 15) * 4;
            const float4 v = *(const float4*)(W + (size_t)(k0 + k) * NOUT + n4);
            *(float4*)&Bs[k][n4] = v;
        }
        __syncthreads();
        #pragma unroll
        for (int kk = 0; kk < 32; ++kk) {
            float4 a = *(const float4*)&As[kk][row0];
            float4 bv = *(const float4*)&Bs[kk][col];
            float ar[4] = {a.x, a.y, a.z, a.w};
            float bc[4] = {bv.x, bv.y, bv.z, bv.w};
            #pragma unroll
            for (int r = 0; r < 4; ++r)
                #pragma unroll
                for (int c = 0; c < 4; ++c)
                    acc[r][c] += ar[r] * bc[c];
        }
        __syncthreads();
    }
    float4 bias = *(const float4*)(b + col);
    float bb[4] = {bias.x, bias.y, bias.z, bias.w};
    #pragma unroll
    for (int r = 0; r < 4; ++r) {
        int gr = br + row0 + r;
        if (gr < M) {
            float4 o = {acc[r][0] + bb[0], acc[r][1] + bb[1],
                        acc[r][2] + bb[2], acc[r][3] + bb[3]};
            *(float4*)(C + (size_t)gr * NOUT + col) = o;
        }
    }
}

// ---------- padded-CSR fill ----------
__global__ void fill_kernel(const int* __restrict__ s, const int* __restrict__ t,
                            int* __restrict__ cnt, int* __restrict__ slots,
                            int cap, int nE)
{
    int e = blockIdx.x * blockDim.x + threadIdx.x;
    if (e >= nE) return;
    int si = s[e];
    int c = atomicAdd(&cnt[si], 1);
    if (c < cap) slots[(size_t)si * cap + c] = t[e];
}

// ---------- per-node scalar dots: x1 = x.a1 ; w2 = exp(leaky(x.a1 + x.a2s)) ; h1 = h.a2o ----------
__global__ void node_dots(const float* __restrict__ x, const float* __restrict__ h,
                          const float* __restrict__ a1, const float* __restrict__ a2s,
                          const float* __restrict__ a2o,
                          float* __restrict__ x1, float* __restrict__ w2,
                          float* __restrict__ h1, int N)
{
    int wid = (blockIdx.x * blockDim.x + threadIdx.x) >> 6;
    int lane = threadIdx.x & 63;
    if (wid >= N) return;
    float2 xv  = *(const float2*)(x + (size_t)wid * NHID + lane * 2);
    float2 hv  = *(const float2*)(h + (size_t)wid * NHID + lane * 2);
    float2 a1v = *(const float2*)(a1 + lane * 2);
    float2 a2sv = *(const float2*)(a2s + lane * 2);
    float2 a2ov = *(const float2*)(a2o + lane * 2);
    float s1 = xv.x * a1v.x + xv.y * a1v.y;
    float s2 = xv.x * a2sv.x + xv.y * a2sv.y;
    float s3 = hv.x * a2ov.x + hv.y * a2ov.y;
    #pragma unroll
    for (int m = 32; m; m >>= 1) {
        s1 += __shfl_xor(s1, m, 64);
        s2 += __shfl_xor(s2, m, 64);
        s3 += __shfl_xor(s3, m, 64);
    }
    if (lane == 0) {
        x1[wid] = s1;
        float v = s1 + s2;
        v = v > 0.f ? v : 0.2f * v;
        w2[wid] = __expf(v);
        h1[wid] = s3;
    }
}

// ---------- aggregation + epilogue: one 64-lane wave per target node ----------
// hout[i] = elu( (sum_e w1*h[t_e] + w2[i]*x[i]) / (sum_e w1 + w2[i]) )
__global__ void agg_kernel(const float* __restrict__ x, const float* __restrict__ h,
                           const float* __restrict__ x1, const float* __restrict__ w2,
                           const float* __restrict__ h1,
                           const int* __restrict__ cnt, const int* __restrict__ slots,
                           float* __restrict__ hout, int N, int cap)
{
    int wid = (blockIdx.x * blockDim.x + threadIdx.x) >> 6;
    int lane = threadIdx.x & 63;
    if (wid >= N) return;
    int deg = cnt[wid];
    if (deg > cap) deg = cap;
    const int* sl = slots + (size_t)wid * cap;
    float x1v = x1[wid];
    float accx = 0.f, accy = 0.f, div = 0.f;
    for (int e = 0; e < deg; ++e) {
        int t = sl[e];
        float sc = x1v + h1[t];
        sc = sc > 0.f ? sc : 0.2f * sc;
        float w = __expf(sc);
        div += w;
        const float2 hv = *(const float2*)(h + (size_t)t * NHID + lane * 2);
        accx += w * hv.x;
        accy += w * hv.y;
    }
    float w2v = w2[wid];
    float2 xv = *(const float2*)(x + (size_t)wid * NHID + lane * 2);
    accx += w2v * xv.x;
    accy += w2v * xv.y;
    div += w2v;
    float inv = 1.f / div;
    float ox = accx * inv, oy = accy * inv;
    ox = ox > 0.f ? ox : (__expf(ox) - 1.f);
    oy = oy > 0.f ? oy : (__expf(oy) - 1.f);
    float2 o = {ox, oy};
    *(float2*)(hout + (size_t)wid * NHID + lane * 2) = o;
}

extern "C" void kernel_launch(void* const* d_in, const int* in_sizes, int n_in,
                              void* d_out, int out_size, void* d_ws, size_t ws_size,
                              hipStream_t stream)
{
    const float* x_A  = (const float*)d_in[0];
    const float* x_P  = (const float*)d_in[1];
    const int*   sAP  = (const int*)d_in[2];
    const int*   tAP  = (const int*)d_in[3];
    const int*   sPA  = (const int*)d_in[4];
    const int*   tPA  = (const int*)d_in[5];
    const float* W1_A = (const float*)d_in[6];
    const float* b1_A = (const float*)d_in[7];
    const float* W1_P = (const float*)d_in[8];
    const float* b1_P = (const float*)d_in[9];
    const float* attn1 = (const float*)d_in[10];
    const float* attn2 = (const float*)d_in[11];
    const float* W2   = (const float*)d_in[12];
    const float* b2   = (const float*)d_in[13];
    float* out = (float*)d_out;
    int nE = in_sizes[2];

    char* ws = (char*)d_ws;
    size_t off = 0;
    auto alloc = [&](size_t bytes) -> void* {
        void* p = ws + off;
        off += (bytes + 255) & ~(size_t)255;
        return p;
    };
    float* xA  = (float*)alloc((size_t)NA * NHID * 4);
    float* xP  = (float*)alloc((size_t)NP * NHID * 4);
    float* hA0 = (float*)alloc((size_t)NA * NHID * 4);
    float* hA1 = (float*)alloc((size_t)NA * NHID * 4);
    float* hP  = (float*)alloc((size_t)NP * NHID * 4);
    float* x1A = (float*)alloc(NA * 4);
    float* w2A = (float*)alloc(NA * 4);
    float* h1A = (float*)alloc(NA * 4);
    float* x1P = (float*)alloc(NP * 4);
    float* w2P = (float*)alloc(NP * 4);
    float* h1P = (float*)alloc(NP * 4);
    int* cntA  = (int*)alloc(NA * 4);
    int* cntP  = (int*)alloc(NP * 4);
    int* slotsA = (int*)alloc((size_t)NA * CAP_A * 4);
    int* slotsP = (int*)alloc((size_t)NP * CAP_P * 4);

    // build padded CSR (edge structure reused by all hops)
    hipMemsetAsync(cntA, 0, NA * 4, stream);
    hipMemsetAsync(cntP, 0, NP * 4, stream);
    fill_kernel<<<(nE + 255) / 256, 256, 0, stream>>>(sAP, tAP, cntA, slotsA, CAP_A, nE);
    fill_kernel<<<(nE + 255) / 256, 256, 0, stream>>>(sPA, tPA, cntP, slotsP, CAP_P, nE);

    // input projections
    proj_kernel<<<(NA + 63) / 64, 256, 0, stream>>>(x_A, W1_A, b1_A, xA, NA);
    proj_kernel<<<(NP + 63) / 64, 256, 0, stream>>>(x_P, W1_P, b1_P, xP, NP);

    const float* hA_cur = xA;
    const float* hP_cur = xP;
    float* hAbuf[2] = {hA0, hA1};

    for (int i = 0; i < HOPS; ++i) {
        const float* a1A = attn1 + (size_t)(i * 2 + 0) * NHID;
        const float* a2A = attn2 + (size_t)(i * 2 + 0) * NHID;
        const float* a1P = attn1 + (size_t)(i * 2 + 1) * NHID;
        const float* a2P = attn2 + (size_t)(i * 2 + 1) * NHID;

        node_dots<<<(NA + 3) / 4, 256, 0, stream>>>(xA, hA_cur, a1A, a2A, a2P,
                                                    x1A, w2A, h1A, NA);
        node_dots<<<(NP + 3) / 4, 256, 0, stream>>>(xP, hP_cur, a1P, a2P, a2A,
                                                    x1P, w2P, h1P, NP);

        float* hA_next = hAbuf[i & 1];
        // A-direction: targets A, gathers from hP_cur
        agg_kernel<<<(NA + 3) / 4, 256, 0, stream>>>(xA, hP_cur, x1A, w2A, h1P,
                                                     cntA, slotsA, hA_next, NA, CAP_A);
        // P-direction: targets P, gathers from hA_cur (old hA). Skipped on last hop.
        if (i < HOPS - 1) {
            agg_kernel<<<(NP + 3) / 4, 256, 0, stream>>>(xP, hA_cur, x1P, w2P, h1A,
                                                         cntP, slotsP, hP, NP, CAP_P);
        }
        hA_cur = hA_next;
        hP_cur = hP;
    }

    out_kernel<<<(NA + 63) / 64, 256, 0, stream>>>(hA_cur, W2, b2, out, NA);
}

// Round 2
// 501.844 us; speedup vs baseline: 1.3805x; 1.3805x over previous
//
#include <hip/hip_runtime.h>
#include <hip/hip_bf16.h>

#define HOPS 3
#define NA 50000
#define NP 100000
#define NIN 256
#define NHID 128
#define NOUT 64
#define CAP_A 64
#define CAP_P 40

typedef __attribute__((ext_vector_type(8))) short bf16x8;
typedef __attribute__((ext_vector_type(4))) float f32x4;

__device__ inline short f2bf(float f) {
    __hip_bfloat16 h = __float2bfloat16(f);
    return *reinterpret_cast<short*>(&h);
}

// ---------- W transpose+convert: Wt[n][k] = bf16(W[k][n]), W:[K][NHID] ----------
__global__ void wt_prep(const float* __restrict__ W, short* __restrict__ Wt, int K)
{
    int idx = blockIdx.x * 256 + threadIdx.x;
    if (idx >= NHID * K) return;
    int n = idx / K, k = idx - n * K;
    Wt[idx] = f2bf(W[(size_t)k * NHID + n]);
}

// ---------- projection via MFMA: C[M,128] = relu(A[M,256] @ W + b) ----------
// block: 256 thr (4 waves), tile 64 rows x 128 cols, K-step 32.
// Wt: [NHID][NIN] bf16 (pre-transposed). MFMA 16x16x32 bf16:
//   A-frag: row = l&15, k = (l>>4)*8 + j ; B-frag: col = l&15, same k
//   D: col = l&15, row = (l>>4)*4 + j      [m89-verified]
__global__ __launch_bounds__(256) void proj_mfma(const float* __restrict__ A,
                                                 const short* __restrict__ Wt,
                                                 const float* __restrict__ b,
                                                 float* __restrict__ C, int M)
{
    __shared__ short Alds[64][40];    // stride 80B: 16B-aligned, 2-way-free banks
    __shared__ short Wlds[128][40];
    int tid = threadIdx.x;
    int br = blockIdx.x * 64;
    int wv = tid >> 6;
    int l = tid & 63;
    int fl = l & 15;
    int kg = l >> 4;

    // staging indices
    int sr = tid >> 2;            // 0..63 row
    int skp = (tid & 3) * 8;      // k-part 0/8/16/24
    int sgr = br + sr; if (sgr >= M) sgr = M - 1;
    int sn = tid >> 1;            // 0..127 col of Wt
    int skq = (tid & 1) * 16;     // 0/16

    f32x4 acc[8];
    #pragma unroll
    for (int c = 0; c < 8; ++c) acc[c] = (f32x4){0.f, 0.f, 0.f, 0.f};

    for (int k0 = 0; k0 < NIN; k0 += 32) {
        // stage A tile 64x32 (f32 -> bf16)
        const float4* ap = (const float4*)(A + (size_t)sgr * NIN + k0 + skp);
        float4 v0 = ap[0], v1 = ap[1];
        union { short s[8]; int4 v; } pk;
        pk.s[0] = f2bf(v0.x); pk.s[1] = f2bf(v0.y);
        pk.s[2] = f2bf(v0.z); pk.s[3] = f2bf(v0.w);
        pk.s[4] = f2bf(v1.x); pk.s[5] = f2bf(v1.y);
        pk.s[6] = f2bf(v1.z); pk.s[7] = f2bf(v1.w);
        *(int4*)&Alds[sr][skp] = pk.v;
        // stage Wt tile 128x32 (bf16 copy)
        const int4* wp = (const int4*)(Wt + (size_t)sn * NIN + k0 + skq);
        int4 w0 = wp[0], w1 = wp[1];
        *(int4*)&Wlds[sn][skq] = w0;
        *(int4*)&Wlds[sn][skq + 8] = w1;
        __syncthreads();

        bf16x8 afr = *(bf16x8*)&Alds[wv * 16 + fl][kg * 8];
        #pragma unroll
        for (int c = 0; c < 8; ++c) {
            bf16x8 bfr = *(bf16x8*)&Wlds[c * 16 + fl][kg * 8];
            acc[c] = __builtin_amdgcn_mfma_f32_16x16x32_bf16(afr, bfr, acc[c], 0, 0, 0);
        }
        __syncthreads();
    }

    int m0 = wv * 16;
    int rj = (l >> 4) * 4;
    #pragma unroll
    for (int c = 0; c < 8; ++c) {
        int col = c * 16 + fl;
        float bb = b[col];
        #pragma unroll
        for (int j = 0; j < 4; ++j) {
            int grow = br + m0 + rj + j;
            if (grow < M) {
                float v = acc[c][j] + bb;
                C[(size_t)grow * NHID + col] = fmaxf(v, 0.f);
            }
        }
    }
}

// ---------- output: C[M,64] = A[M,128] @ W[128,64] + b (f32 VALU) ----------
__global__ __launch_bounds__(256) void out_kernel(const float* __restrict__ A,
                                                  const float* __restrict__ W,
                                                  const float* __restrict__ b,
                                                  float* __restrict__ C, int M)
{
    __shared__ float As[32][68];
    __shared__ float Bs[32][68];
    int tid = threadIdx.x;
    int br = blockIdx.x * 64;
    int tx = tid & 15, ty = tid >> 4;
    int col = tx * 4, row0 = ty * 4;
    float acc[4][4] = {};
    for (int k0 = 0; k0 < NHID; k0 += 32) {
        #pragma unroll
        for (int i = 0; i < 2; ++i) {
            int f = tid + i * 256;
            int r = f >> 3;
            int k4 = (f & 7) * 4;
            int gr = br + r; if (gr >= M) gr = M - 1;
            const float4 v = *(const float4*)(A + (size_t)gr * NHID + k0 + k4);
            As[k4 + 0][r] = v.x; As[k4 + 1][r] = v.y;
            As[k4 + 2][r] = v.z; As[k4 + 3][r] = v.w;
        }
        #pragma unroll
        for (int i = 0; i < 2; ++i) {
            int f = tid + i * 256;
            int k = f >> 4;
            int n4 = (f & 15) * 4;
            const float4 v = *(const float4*)(W + (size_t)(k0 + k) * NOUT + n4);
            *(float4*)&Bs[k][n4] = v;
        }
        __syncthreads();
        #pragma unroll
        for (int kk = 0; kk < 32; ++kk) {
            float4 a = *(const float4*)&As[kk][row0];
            float4 bv = *(const float4*)&Bs[kk][col];
            float ar[4] = {a.x, a.y, a.z, a.w};
            float bc[4] = {bv.x, bv.y, bv.z, bv.w};
            #pragma unroll
            for (int r = 0; r < 4; ++r)
                #pragma unroll
                for (int c = 0; c < 4; ++c)
                    acc[r][c] += ar[r] * bc[c];
        }
        __syncthreads();
    }
    float4 bias = *(const float4*)(b + col);
    float bb[4] = {bias.x, bias.y, bias.z, bias.w};
    #pragma unroll
    for (int r = 0; r < 4; ++r) {
        int gr = br + row0 + r;
        if (gr < M) {
            float4 o = {acc[r][0] + bb[0], acc[r][1] + bb[1],
                        acc[r][2] + bb[2], acc[r][3] + bb[3]};
            *(float4*)(C + (size_t)gr * NOUT + col) = o;
        }
    }
}

// ---------- padded-CSR fill ----------
__global__ void fill_kernel(const int* __restrict__ s, const int* __restrict__ t,
                            int* __restrict__ cnt, int* __restrict__ slots,
                            int cap, int nE)
{
    int e = blockIdx.x * blockDim.x + threadIdx.x;
    if (e >= nE) return;
    int si = s[e];
    int c = atomicAdd(&cnt[si], 1);
    if (c < cap) slots[(size_t)si * cap + c] = t[e];
}

// ---------- per-node scalar dots ----------
__global__ void node_dots(const float* __restrict__ x, const float* __restrict__ h,
                          const float* __restrict__ a1, const float* __restrict__ a2s,
                          const float* __restrict__ a2o,
                          float* __restrict__ x1, float* __restrict__ w2,
                          float* __restrict__ h1, int N)
{
    int wid = (blockIdx.x * blockDim.x + threadIdx.x) >> 6;
    int lane = threadIdx.x & 63;
    if (wid >= N) return;
    float2 xv  = *(const float2*)(x + (size_t)wid * NHID + lane * 2);
    float2 hv  = *(const float2*)(h + (size_t)wid * NHID + lane * 2);
    float2 a1v = *(const float2*)(a1 + lane * 2);
    float2 a2sv = *(const float2*)(a2s + lane * 2);
    float2 a2ov = *(const float2*)(a2o + lane * 2);
    float s1 = xv.x * a1v.x + xv.y * a1v.y;
    float s2 = xv.x * a2sv.x + xv.y * a2sv.y;
    float s3 = hv.x * a2ov.x + hv.y * a2ov.y;
    #pragma unroll
    for (int m = 32; m; m >>= 1) {
        s1 += __shfl_xor(s1, m, 64);
        s2 += __shfl_xor(s2, m, 64);
        s3 += __shfl_xor(s3, m, 64);
    }
    if (lane == 0) {
        x1[wid] = s1;
        float v = s1 + s2;
        v = v > 0.f ? v : 0.2f * v;
        w2[wid] = __expf(v);
        h1[wid] = s3;
    }
}

// ---------- aggregation: one wave per node, 4 edge-groups x 16 feature-lanes ----------
// hout[i] = elu( (sum_e w1*h[t_e] + w2[i]*x[i]) / (sum_e w1 + w2[i]) )
__global__ void agg_kernel(const float* __restrict__ x, const float* __restrict__ h,
                           const float* __restrict__ x1, const float* __restrict__ w2,
                           const float* __restrict__ h1,
                           const int* __restrict__ cnt, const int* __restrict__ slots,
                           float* __restrict__ hout, int N, int cap)
{
    int wid = (blockIdx.x * blockDim.x + threadIdx.x) >> 6;
    int lane = threadIdx.x & 63;
    if (wid >= N) return;
    int g = lane >> 4;          // edge group 0..3
    int fl = lane & 15;         // feature lane: owns 8 floats
    int deg = cnt[wid];
    if (deg > cap) deg = cap;
    const int* sl = slots + (size_t)wid * cap;
    float x1v = x1[wid];
    float4 a0 = {0, 0, 0, 0}, a1 = {0, 0, 0, 0};
    float div = 0.f;

    int e = g;
    int tnext = (e < deg) ? sl[e] : -1;
    while (tnext >= 0) {
        int t = tnext;
        e += 4;
        tnext = (e < deg) ? sl[e] : -1;   // prefetch next slot
        float sc = x1v + h1[t];
        sc = sc > 0.f ? sc : 0.2f * sc;
        float w = __expf(sc);
        div += w;
        const float4* hp = (const float4*)(h + (size_t)t * NHID + fl * 8);
        float4 h0 = hp[0], h1v = hp[1];
        a0.x += w * h0.x;  a0.y += w * h0.y;  a0.z += w * h0.z;  a0.w += w * h0.w;
        a1.x += w * h1v.x; a1.y += w * h1v.y; a1.z += w * h1v.z; a1.w += w * h1v.w;
    }
    // reduce across the 4 edge groups (lanes xor 16, 32)
    #pragma unroll
    for (int m = 16; m <= 32; m <<= 1) {
        a0.x += __shfl_xor(a0.x, m, 64); a0.y += __shfl_xor(a0.y, m, 64);
        a0.z += __shfl_xor(a0.z, m, 64); a0.w += __shfl_xor(a0.w, m, 64);
        a1.x += __shfl_xor(a1.x, m, 64); a1.y += __shfl_xor(a1.y, m, 64);
        a1.z += __shfl_xor(a1.z, m, 64); a1.w += __shfl_xor(a1.w, m, 64);
        div  += __shfl_xor(div, m, 64);
    }
    if (g == 0) {
        float w2v = w2[wid];
        const float4* xp = (const float4*)(x + (size_t)wid * NHID + fl * 8);
        float4 x0 = xp[0], x1f = xp[1];
        a0.x += w2v * x0.x;  a0.y += w2v * x0.y;  a0.z += w2v * x0.z;  a0.w += w2v * x0.w;
        a1.x += w2v * x1f.x; a1.y += w2v * x1f.y; a1.z += w2v * x1f.z; a1.w += w2v * x1f.w;
        div += w2v;
        float inv = 1.f / div;
        float o[8] = {a0.x * inv, a0.y * inv, a0.z * inv, a0.w * inv,
                      a1.x * inv, a1.y * inv, a1.z * inv, a1.w * inv};
        #pragma unroll
        for (int i = 0; i < 8; ++i)
            o[i] = o[i] > 0.f ? o[i] : (__expf(o[i]) - 1.f);
        float4 s0 = {o[0], o[1], o[2], o[3]};
        float4 s1 = {o[4], o[5], o[6], o[7]};
        float4* op = (float4*)(hout + (size_t)wid * NHID + fl * 8);
        op[0] = s0;
        op[1] = s1;
    }
}

extern "C" void kernel_launch(void* const* d_in, const int* in_sizes, int n_in,
                              void* d_out, int out_size, void* d_ws, size_t ws_size,
                              hipStream_t stream)
{
    const float* x_A  = (const float*)d_in[0];
    const float* x_P  = (const float*)d_in[1];
    const int*   sAP  = (const int*)d_in[2];
    const int*   tAP  = (const int*)d_in[3];
    const int*   sPA  = (const int*)d_in[4];
    const int*   tPA  = (const int*)d_in[5];
    const float* W1_A = (const float*)d_in[6];
    const float* b1_A = (const float*)d_in[7];
    const float* W1_P = (const float*)d_in[8];
    const float* b1_P = (const float*)d_in[9];
    const float* attn1 = (const float*)d_in[10];
    const float* attn2 = (const float*)d_in[11];
    const float* W2   = (const float*)d_in[12];
    const float* b2   = (const float*)d_in[13];
    float* out = (float*)d_out;
    int nE = in_sizes[2];

    char* ws = (char*)d_ws;
    size_t off = 0;
    auto alloc = [&](size_t bytes) -> void* {
        void* p = ws + off;
        off += (bytes + 255) & ~(size_t)255;
        return p;
    };
    float* xA  = (float*)alloc((size_t)NA * NHID * 4);
    float* xP  = (float*)alloc((size_t)NP * NHID * 4);
    float* hA0 = (float*)alloc((size_t)NA * NHID * 4);
    float* hA1 = (float*)alloc((size_t)NA * NHID * 4);
    float* hP  = (float*)alloc((size_t)NP * NHID * 4);
    float* x1A = (float*)alloc(NA * 4);
    float* w2A = (float*)alloc(NA * 4);
    float* h1A = (float*)alloc(NA * 4);
    float* x1P = (float*)alloc(NP * 4);
    float* w2P = (float*)alloc(NP * 4);
    float* h1P = (float*)alloc(NP * 4);
    int* cntA  = (int*)alloc(NA * 4);
    int* cntP  = (int*)alloc(NP * 4);
    int* slotsA = (int*)alloc((size_t)NA * CAP_A * 4);
    int* slotsP = (int*)alloc((size_t)NP * CAP_P * 4);
    short* WtA = (short*)alloc((size_t)NHID * NIN * 2);
    short* WtP = (short*)alloc((size_t)NHID * NIN * 2);

    // build padded CSR (edge structure reused by all hops)
    hipMemsetAsync(cntA, 0, NA * 4, stream);
    hipMemsetAsync(cntP, 0, NP * 4, stream);
    fill_kernel<<<(nE + 255) / 256, 256, 0, stream>>>(sAP, tAP, cntA, slotsA, CAP_A, nE);
    fill_kernel<<<(nE + 255) / 256, 256, 0, stream>>>(sPA, tPA, cntP, slotsP, CAP_P, nE);

    // W1 -> bf16 transposed, then MFMA projections
    wt_prep<<<(NHID * NIN + 255) / 256, 256, 0, stream>>>(W1_A, WtA, NIN);
    wt_prep<<<(NHID * NIN + 255) / 256, 256, 0, stream>>>(W1_P, WtP, NIN);
    proj_mfma<<<(NA + 63) / 64, 256, 0, stream>>>(x_A, WtA, b1_A, xA, NA);
    proj_mfma<<<(NP + 63) / 64, 256, 0, stream>>>(x_P, WtP, b1_P, xP, NP);

    const float* hA_cur = xA;
    const float* hP_cur = xP;
    float* hAbuf[2] = {hA0, hA1};

    for (int i = 0; i < HOPS; ++i) {
        const float* a1A = attn1 + (size_t)(i * 2 + 0) * NHID;
        const float* a2A = attn2 + (size_t)(i * 2 + 0) * NHID;
        const float* a1P = attn1 + (size_t)(i * 2 + 1) * NHID;
        const float* a2P = attn2 + (size_t)(i * 2 + 1) * NHID;

        node_dots<<<(NA + 3) / 4, 256, 0, stream>>>(xA, hA_cur, a1A, a2A, a2P,
                                                    x1A, w2A, h1A, NA);
        node_dots<<<(NP + 3) / 4, 256, 0, stream>>>(xP, hP_cur, a1P, a2P, a2A,
                                                    x1P, w2P, h1P, NP);

        float* hA_next = hAbuf[i & 1];
        // A-direction: targets A, gathers from hP_cur
        agg_kernel<<<(NA + 3) / 4, 256, 0, stream>>>(xA, hP_cur, x1A, w2A, h1P,
                                                     cntA, slotsA, hA_next, NA, CAP_A);
        // P-direction: targets P, gathers from hA_cur. Skipped on last hop.
        if (i < HOPS - 1) {
            agg_kernel<<<(NP + 3) / 4, 256, 0, stream>>>(xP, hA_cur, x1P, w2P, h1A,
                                                         cntP, slotsP, hP, NP, CAP_P);
        }
        hA_cur = hA_next;
        hP_cur = hP;
    }

    out_kernel<<<(NA + 63) / 64, 256, 0, stream>>>(hA_cur, W2, b2, out, NA);
}